// Round 1
// baseline (279.919 us; speedup 1.0000x reference)
//
#include <hip/hip_runtime.h>
#include <hip/hip_bf16.h>

typedef __bf16 bf16x8 __attribute__((ext_vector_type(8)));
typedef float f32x4 __attribute__((ext_vector_type(4)));

static __device__ __forceinline__ unsigned short f2bf(float x) {
    __hip_bfloat16 b = __float2bfloat16(x);
    return __builtin_bit_cast(unsigned short, b);
}
static __device__ __forceinline__ float bf2f(unsigned short u) {
    __hip_bfloat16 b = __builtin_bit_cast(__hip_bfloat16, u);
    return __bfloat162float(b);
}

static __device__ __forceinline__ void gload_lds16(const void* g, void* l) {
    __builtin_amdgcn_global_load_lds(
        (const __attribute__((address_space(1))) void*)g,
        (__attribute__((address_space(3))) void*)l, 16, 0, 0);
}

// ---------------- convert fp32 -> bf16 (vectorized) ----------------
__global__ __launch_bounds__(256) void cvt_f32_bf16(const float* __restrict__ in,
                                                    unsigned short* __restrict__ out,
                                                    int n4) {
    int i = blockIdx.x * blockDim.x + threadIdx.x;
    if (i < n4) {
        float4 v = reinterpret_cast<const float4*>(in)[i];
        ushort4 o;
        o.x = f2bf(v.x); o.y = f2bf(v.y); o.z = f2bf(v.z); o.w = f2bf(v.w);
        reinterpret_cast<ushort4*>(out)[i] = o;
    }
}

// ---------------- transpose (K x N fp32) -> (N x K bf16) ----------------
__global__ void transpose_bf16(const float* __restrict__ in,
                               unsigned short* __restrict__ out,
                               int K, int N) {
    __shared__ float tile[32][33];
    int k0 = blockIdx.x * 32, n0 = blockIdx.y * 32;
    int tx = threadIdx.x, ty = threadIdx.y;  // (32, 8)
    for (int i = ty; i < 32; i += 8) tile[i][tx] = in[(size_t)(k0 + i) * N + n0 + tx];
    __syncthreads();
    for (int i = ty; i < 32; i += 8)
        out[(size_t)(n0 + i) * K + k0 + tx] = f2bf(tile[tx][i]);
}

// ---------------- off/attw GEMMs + softmax + grid-sample coefficients ----------------
__global__ __launch_bounds__(256) void offw_kernel(
    const float* __restrict__ query, const float* __restrict__ w_off,
    const float* __restrict__ b_off, const float* __restrict__ w_attw,
    const float* __restrict__ b_attw, int* __restrict__ idx_out,
    float* __restrict__ c0_out, float* __restrict__ c1_out) {
    const int n = blockIdx.x;      // 0..8191 (b*L + l)
    const int l = n & 4095;
    const int tid = threadIdx.x;
    __shared__ float qs[1024];
    __shared__ float offL[128];
    __shared__ float attL[64];
    {
        const float4* q4 = reinterpret_cast<const float4*>(query + (size_t)n * 1024);
        reinterpret_cast<float4*>(qs)[tid] = q4[tid];
    }
    __syncthreads();
    if (tid < 128) {
        float acc = b_off[tid];
        const float* w = w_off + tid;
        #pragma unroll 8
        for (int k = 0; k < 1024; ++k) acc += qs[k] * w[(size_t)k * 128];
        offL[tid] = acc;
    } else if (tid < 192) {
        int col = tid - 128;
        float acc = b_attw[col];
        const float* w = w_attw + col;
        #pragma unroll 8
        for (int k = 0; k < 1024; ++k) acc += qs[k] * w[(size_t)k * 64];
        attL[col] = acc;
    }
    __syncthreads();
    if (tid < 64) {
        int h = tid >> 2, p = tid & 3;
        float l0 = attL[h * 4 + 0], l1 = attL[h * 4 + 1];
        float l2 = attL[h * 4 + 2], l3 = attL[h * 4 + 3];
        float mx = fmaxf(fmaxf(l0, l1), fmaxf(l2, l3));
        float e0 = expf(l0 - mx), e1 = expf(l1 - mx), e2 = expf(l2 - mx), e3 = expf(l3 - mx);
        float esum = e0 + e1 + e2 + e3;
        float aw = ((p == 0) ? e0 : (p == 1) ? e1 : (p == 2) ? e2 : e3) / esum;
        float o0 = offL[h * 8 + p * 2], o1 = offL[h * 8 + p * 2 + 1];
        float sx = fminf(fmaxf(o0, 0.f), 1.f);
        float ry = (float)l / 4095.0f;
        float sy = fminf(fmaxf(ry + o1, 0.f), 1.f);
        float ix = ((sx + 1.f) * 4096.f - 1.f) * 0.5f;
        float iy = sy * 0.5f;
        float x0f = floorf(ix);
        float fx = ix - x0f;
        int x0 = (int)x0f;
        int x1 = x0 + 1;
        float m0 = (x0 >= 0 && x0 < 4096) ? 1.f : 0.f;
        float m1 = (x1 >= 0 && x1 < 4096) ? 1.f : 0.f;
        float y0f = floorf(iy);
        float fy = iy - y0f;
        float hy = ((y0f == 0.f) ? (1.f - fy) : 0.f) + ((y0f == -1.f) ? fy : 0.f);
        float c0 = aw * (1.f - fx) * m0 * hy;
        float c1 = aw * fx * m1 * hy;
        int x0c = x0 < 0 ? 0 : (x0 > 4095 ? 4095 : x0);
        int o = n * 64 + tid;
        idx_out[o] = x0c;
        c0_out[o] = c0;
        c1_out[o] = c1;
    }
}

// ---------------- gather + weighted combine ----------------
__global__ __launch_bounds__(256) void sample_kernel(
    const unsigned short* __restrict__ vproj,  // (B*L, 1024) bf16
    const int* __restrict__ idx, const float* __restrict__ c0a,
    const float* __restrict__ c1a, unsigned short* __restrict__ s_out) {
    const int n = blockIdx.x;
    const int tid = threadIdx.x;
    __shared__ int sIdx[64];
    __shared__ float sC0[64], sC1[64];
    if (tid < 64) {
        int o = n * 64 + tid;
        sIdx[tid] = idx[o];
        sC0[tid] = c0a[o];
        sC1[tid] = c1a[o];
    }
    __syncthreads();
    const int d = tid * 4;
    const int h = tid >> 4;
    const size_t vb = (size_t)(n >> 12) * 4096 * 1024;
    float a0 = 0.f, a1 = 0.f, a2 = 0.f, a3 = 0.f;
    #pragma unroll
    for (int p = 0; p < 4; ++p) {
        int e = h * 4 + p;
        int x0 = sIdx[e];
        float c0 = sC0[e], c1 = sC1[e];
        int x1 = (x0 + 1 > 4095) ? 4095 : x0 + 1;
        ushort4 v0 = *reinterpret_cast<const ushort4*>(vproj + vb + (size_t)x0 * 1024 + d);
        ushort4 v1 = *reinterpret_cast<const ushort4*>(vproj + vb + (size_t)x1 * 1024 + d);
        a0 += c0 * bf2f(v0.x) + c1 * bf2f(v1.x);
        a1 += c0 * bf2f(v0.y) + c1 * bf2f(v1.y);
        a2 += c0 * bf2f(v0.z) + c1 * bf2f(v1.z);
        a3 += c0 * bf2f(v0.w) + c1 * bf2f(v1.w);
    }
    ushort4 o;
    o.x = f2bf(a0); o.y = f2bf(a1); o.z = f2bf(a2); o.w = f2bf(a3);
    *reinterpret_cast<ushort4*>(s_out + (size_t)n * 1024 + d) = o;
}

// ---------------- bf16 MFMA GEMM: C = A(MxK) * Bt(NxK)^T + bias ----------------
// m97-style: 128x128 tile, BK=32, 4 waves in 2x2, 16x16x32 MFMA.
template <bool OUT_F32>
__global__ __launch_bounds__(256, 2) void gemm_bt(
    const unsigned short* __restrict__ A,   // M x K bf16
    const unsigned short* __restrict__ Bt,  // N x K bf16
    const float* __restrict__ bias,         // N
    void* __restrict__ C, int M, int N, int K) {
    __shared__ unsigned short As[128 * 32];  // [m][k]
    __shared__ unsigned short Bs[128 * 32];  // [n][k]
    const int tid = threadIdx.x;
    const int lane = tid & 63;
    const int wave = tid >> 6;
    const int bm = blockIdx.x * 128;
    const int bn = blockIdx.y * 128;
    const int wr = wave >> 1;  // 0..1
    const int wc = wave & 1;   // 0..1
    const int r = lane & 15;
    const int kq = lane >> 4;  // 0..3

    f32x4 acc[4][4];
    #pragma unroll
    for (int i = 0; i < 4; ++i)
        #pragma unroll
        for (int j = 0; j < 4; ++j) acc[i][j] = (f32x4){0.f, 0.f, 0.f, 0.f};

    const int c1 = tid;        // chunk ids (16B each); tile = 512 chunks
    const int c2 = 256 + tid;
    const int cb1 = wave * 64;         // wave-uniform LDS chunk base
    const int cb2 = 256 + wave * 64;

    for (int k0 = 0; k0 < K; k0 += 32) {
        const unsigned short* Ab = A + (size_t)bm * K + k0;
        const unsigned short* Bb = Bt + (size_t)bn * K + k0;
        // stage A (128x32 bf16 = 512 x 16B chunks), chunk c: row c>>2, koff (c&3)*8
        gload_lds16(Ab + (size_t)(c1 >> 2) * K + (c1 & 3) * 8, &As[cb1 * 8]);
        gload_lds16(Ab + (size_t)(c2 >> 2) * K + (c2 & 3) * 8, &As[cb2 * 8]);
        gload_lds16(Bb + (size_t)(c1 >> 2) * K + (c1 & 3) * 8, &Bs[cb1 * 8]);
        gload_lds16(Bb + (size_t)(c2 >> 2) * K + (c2 & 3) * 8, &Bs[cb2 * 8]);
        __syncthreads();  // drains vmcnt before barrier

        bf16x8 af[4], bfr[4];
        #pragma unroll
        for (int i = 0; i < 4; ++i)
            af[i] = *reinterpret_cast<const bf16x8*>(&As[(wr * 64 + i * 16 + r) * 32 + kq * 8]);
        #pragma unroll
        for (int j = 0; j < 4; ++j)
            bfr[j] = *reinterpret_cast<const bf16x8*>(&Bs[(wc * 64 + j * 16 + r) * 32 + kq * 8]);
        #pragma unroll
        for (int i = 0; i < 4; ++i)
            #pragma unroll
            for (int j = 0; j < 4; ++j)
                acc[i][j] = __builtin_amdgcn_mfma_f32_16x16x32_bf16(af[i], bfr[j], acc[i][j], 0, 0, 0);
        __syncthreads();  // protect LDS before next stage
    }

    float* Cf = (float*)C;
    unsigned short* Cb = (unsigned short*)C;
    #pragma unroll
    for (int i = 0; i < 4; ++i) {
        int row0 = bm + wr * 64 + i * 16 + kq * 4;
        #pragma unroll
        for (int j = 0; j < 4; ++j) {
            int col = bn + wc * 64 + j * 16 + r;
            float bs = bias[col];
            #pragma unroll
            for (int rr = 0; rr < 4; ++rr) {
                float val = acc[i][j][rr] + bs;
                size_t off = (size_t)(row0 + rr) * N + col;
                if (OUT_F32) Cf[off] = val;
                else Cb[off] = f2bf(val);
            }
        }
    }
}

extern "C" void kernel_launch(void* const* d_in, const int* in_sizes, int n_in,
                              void* d_out, int out_size, void* d_ws, size_t ws_size,
                              hipStream_t stream) {
    const float* query  = (const float*)d_in[0];
    // d_in[1] = key   (unused: dead code in reference)
    const float* value  = (const float*)d_in[2];
    // d_in[3] = w_qk, d_in[4] = b_qk (dead code)
    const float* w_value = (const float*)d_in[5];
    const float* b_value = (const float*)d_in[6];
    const float* w_off   = (const float*)d_in[7];
    const float* b_off   = (const float*)d_in[8];
    const float* w_attw  = (const float*)d_in[9];
    const float* b_attw  = (const float*)d_in[10];
    const float* w_out   = (const float*)d_in[11];
    const float* b_out   = (const float*)d_in[12];
    float* out = (float*)d_out;

    char* w = (char*)d_ws;
    unsigned short* Vbf   = (unsigned short*)(w);                       // 16 MB
    unsigned short* WvT   = (unsigned short*)(w + (16ull << 20));       // 2 MB
    unsigned short* WoT   = (unsigned short*)(w + (18ull << 20));       // 2 MB
    unsigned short* Vproj = (unsigned short*)(w + (20ull << 20));       // 16 MB
    unsigned short* S     = (unsigned short*)(w + (36ull << 20));       // 16 MB
    int*            Idx   = (int*)(w + (52ull << 20));                  // 2 MB
    float*          C0    = (float*)(w + (54ull << 20));                // 2 MB
    float*          C1    = (float*)(w + (56ull << 20));                // 2 MB

    // 1. value -> bf16
    cvt_f32_bf16<<<8192, 256, 0, stream>>>(value, Vbf, 2097152);
    // 2. weight transposes -> bf16 (N x K)
    dim3 tb(32, 8);
    transpose_bf16<<<dim3(32, 32), tb, 0, stream>>>(w_value, WvT, 1024, 1024);
    transpose_bf16<<<dim3(32, 32), tb, 0, stream>>>(w_out, WoT, 1024, 1024);
    // 3. offsets + attention weights + sample coefficients
    offw_kernel<<<8192, 256, 0, stream>>>(query, w_off, b_off, w_attw, b_attw, Idx, C0, C1);
    // 4. v = value @ w_value + b_value   (bf16 out)
    gemm_bt<false><<<dim3(64, 8), 256, 0, stream>>>(Vbf, WvT, b_value, Vproj, 8192, 1024, 1024);
    // 5. gather + weighted combine -> s (bf16)
    sample_kernel<<<8192, 256, 0, stream>>>(Vproj, Idx, C0, C1, S);
    // 6. out = s @ w_out + b_out  (fp32 out)
    gemm_bt<true><<<dim3(64, 8), 256, 0, stream>>>(S, WoT, b_out, out, 8192, 1024, 1024);
}

// Round 2
// 193.282 us; speedup vs baseline: 1.4482x; 1.4482x over previous
//
#include <hip/hip_runtime.h>
#include <hip/hip_bf16.h>

typedef __bf16 bf16x8 __attribute__((ext_vector_type(8)));
typedef float f32x4 __attribute__((ext_vector_type(4)));

static __device__ __forceinline__ unsigned short f2bf(float x) {
    __hip_bfloat16 b = __float2bfloat16(x);
    return __builtin_bit_cast(unsigned short, b);
}
static __device__ __forceinline__ float bf2f(unsigned short u) {
    __hip_bfloat16 b = __builtin_bit_cast(__hip_bfloat16, u);
    return __bfloat162float(b);
}

static __device__ __forceinline__ void gload_lds16(const void* g, void* l) {
    __builtin_amdgcn_global_load_lds(
        (const __attribute__((address_space(1))) void*)g,
        (__attribute__((address_space(3))) void*)l, 16, 0, 0);
}

// ---------------- convert fp32 -> bf16, only rows [1920,4096) per batch ----------------
__global__ __launch_bounds__(256) void cvt_slice(const float* __restrict__ in,
                                                 unsigned short* __restrict__ out) {
    int g = blockIdx.x * 256 + threadIdx.x;      // 2*2176*256 total
    int r4 = g >> 8;                              // sliced row id
    int cpos = g & 255;                           // float4 within row
    int b = r4 / 2176;
    int l = 1920 + (r4 % 2176);
    size_t off4 = (size_t)(b * 4096 + l) * 256 + cpos;
    float4 v = reinterpret_cast<const float4*>(in)[off4];
    ushort4 o;
    o.x = f2bf(v.x); o.y = f2bf(v.y); o.z = f2bf(v.z); o.w = f2bf(v.w);
    reinterpret_cast<ushort4*>(out)[off4] = o;
}

// ---------------- transpose (K x N fp32) -> (N x K bf16) ----------------
__global__ void transpose_bf16(const float* __restrict__ in,
                               unsigned short* __restrict__ out,
                               int K, int N) {
    __shared__ float tile[32][33];
    int k0 = blockIdx.x * 32, n0 = blockIdx.y * 32;
    int tx = threadIdx.x, ty = threadIdx.y;  // (32, 8)
    for (int i = ty; i < 32; i += 8) tile[i][tx] = in[(size_t)(k0 + i) * N + n0 + tx];
    __syncthreads();
    for (int i = ty; i < 32; i += 8)
        out[(size_t)(n0 + i) * K + k0 + tx] = f2bf(tile[tx][i]);
}

// ---------------- fp32 GEMM for off/attw logits: (8192x1024)@(1024x192) ----------------
// lane <-> column (192 threads = 3 waves), 8 block-uniform rows -> q via scalar loads.
__global__ __launch_bounds__(192) void offw_gemm(
    const float* __restrict__ query, const float* __restrict__ w_off,
    const float* __restrict__ b_off, const float* __restrict__ w_attw,
    const float* __restrict__ b_attw, float* __restrict__ logits) {
    const int c = threadIdx.x;            // 0..191
    const int row0 = blockIdx.x * 8;      // 1024 blocks
    const bool isOff = c < 128;
    const float* wb = isOff ? (w_off + c) : (w_attw + (c - 128));
    const int stride = isOff ? 128 : 64;
    const float bias = isOff ? b_off[c] : b_attw[c - 128];
    const float* qbase = query + (size_t)row0 * 1024;

    float acc[8];
    #pragma unroll
    for (int r = 0; r < 8; ++r) acc[r] = 0.f;

    for (int k0 = 0; k0 < 1024; k0 += 8) {
        float qv[8][8];
        #pragma unroll
        for (int r = 0; r < 8; ++r)
            #pragma unroll
            for (int j = 0; j < 8; ++j)
                qv[r][j] = qbase[(size_t)r * 1024 + k0 + j];   // uniform -> s_load
        #pragma unroll
        for (int j = 0; j < 8; ++j) {
            float wv = wb[(size_t)(k0 + j) * stride];
            #pragma unroll
            for (int r = 0; r < 8; ++r) acc[r] += qv[r][j] * wv;
        }
    }
    #pragma unroll
    for (int r = 0; r < 8; ++r)
        logits[(size_t)(row0 + r) * 192 + c] = acc[r] + bias;
}

// ---------------- softmax + grid-sample coefficients ----------------
__global__ __launch_bounds__(256) void coef_kernel(
    const float* __restrict__ logits, int* __restrict__ idx_out,
    float* __restrict__ c0_out, float* __restrict__ c1_out) {
    int g = blockIdx.x * 256 + threadIdx.x;   // 8192*64
    int n = g >> 6, e = g & 63;
    int l = n & 4095;
    int h = e >> 2, p = e & 3;
    const float* L = logits + (size_t)n * 192;
    float l0 = L[128 + h * 4 + 0], l1 = L[128 + h * 4 + 1];
    float l2 = L[128 + h * 4 + 2], l3 = L[128 + h * 4 + 3];
    float mx = fmaxf(fmaxf(l0, l1), fmaxf(l2, l3));
    float e0 = expf(l0 - mx), e1 = expf(l1 - mx), e2 = expf(l2 - mx), e3 = expf(l3 - mx);
    float esum = e0 + e1 + e2 + e3;
    float aw = ((p == 0) ? e0 : (p == 1) ? e1 : (p == 2) ? e2 : e3) / esum;
    float o0 = L[h * 8 + p * 2], o1 = L[h * 8 + p * 2 + 1];
    float sx = fminf(fmaxf(o0, 0.f), 1.f);
    float ry = (float)l / 4095.0f;
    float sy = fminf(fmaxf(ry + o1, 0.f), 1.f);
    float ix = ((sx + 1.f) * 4096.f - 1.f) * 0.5f;
    float iy = sy * 0.5f;
    float x0f = floorf(ix);
    float fx = ix - x0f;
    int x0 = (int)x0f;
    int x1 = x0 + 1;
    float m0 = (x0 >= 0 && x0 < 4096) ? 1.f : 0.f;
    float m1 = (x1 >= 0 && x1 < 4096) ? 1.f : 0.f;
    float y0f = floorf(iy);
    float fy = iy - y0f;
    float hy = ((y0f == 0.f) ? (1.f - fy) : 0.f) + ((y0f == -1.f) ? fy : 0.f);
    float c0 = aw * (1.f - fx) * m0 * hy;
    float c1 = aw * fx * m1 * hy;
    int x0c = x0 < 0 ? 0 : (x0 > 4095 ? 4095 : x0);
    idx_out[g] = x0c;
    c0_out[g] = c0;
    c1_out[g] = c1;
}

// ---------------- gather + weighted combine ----------------
__global__ __launch_bounds__(256) void sample_kernel(
    const unsigned short* __restrict__ vproj,  // (B*L, 1024) bf16
    const int* __restrict__ idx, const float* __restrict__ c0a,
    const float* __restrict__ c1a, unsigned short* __restrict__ s_out) {
    const int n = blockIdx.x;
    const int tid = threadIdx.x;
    __shared__ int sIdx[64];
    __shared__ float sC0[64], sC1[64];
    if (tid < 64) {
        int o = n * 64 + tid;
        sIdx[tid] = idx[o];
        sC0[tid] = c0a[o];
        sC1[tid] = c1a[o];
    }
    __syncthreads();
    const int d = tid * 4;
    const int h = tid >> 4;
    const size_t vb = (size_t)(n >> 12) * 4096 * 1024;
    float a0 = 0.f, a1 = 0.f, a2 = 0.f, a3 = 0.f;
    #pragma unroll
    for (int p = 0; p < 4; ++p) {
        int e = h * 4 + p;
        int x0 = sIdx[e];
        float c0 = sC0[e], c1 = sC1[e];
        int x1 = (x0 + 1 > 4095) ? 4095 : x0 + 1;
        ushort4 v0 = *reinterpret_cast<const ushort4*>(vproj + vb + (size_t)x0 * 1024 + d);
        ushort4 v1 = *reinterpret_cast<const ushort4*>(vproj + vb + (size_t)x1 * 1024 + d);
        a0 += c0 * bf2f(v0.x) + c1 * bf2f(v1.x);
        a1 += c0 * bf2f(v0.y) + c1 * bf2f(v1.y);
        a2 += c0 * bf2f(v0.z) + c1 * bf2f(v1.z);
        a3 += c0 * bf2f(v0.w) + c1 * bf2f(v1.w);
    }
    ushort4 o;
    o.x = f2bf(a0); o.y = f2bf(a1); o.z = f2bf(a2); o.w = f2bf(a3);
    *reinterpret_cast<ushort4*>(s_out + (size_t)n * 1024 + d) = o;
}

// ---------------- bf16 MFMA GEMM: C = A(rows x K) * Bt(NxK)^T + bias ----------------
// m97-style: 128x128 tile, BK=32, 4 waves in 2x2, 16x16x32 MFMA.
// Row base = rowoff + blockIdx.z*zstride + blockIdx.x*128 (for batch-sliced runs).
template <bool OUT_F32>
__global__ __launch_bounds__(256, 2) void gemm_bt(
    const unsigned short* __restrict__ A,   // bf16, rows x K
    const unsigned short* __restrict__ Bt,  // N x K bf16
    const float* __restrict__ bias,         // N
    void* __restrict__ C, int rowoff, int zstride, int N, int K) {
    __shared__ unsigned short As[128 * 32];  // [m][k]
    __shared__ unsigned short Bs[128 * 32];  // [n][k]
    const int tid = threadIdx.x;
    const int lane = tid & 63;
    const int wave = tid >> 6;
    const int bm = rowoff + blockIdx.z * zstride + blockIdx.x * 128;
    const int bn = blockIdx.y * 128;
    const int wr = wave >> 1;  // 0..1
    const int wc = wave & 1;   // 0..1
    const int r = lane & 15;
    const int kq = lane >> 4;  // 0..3

    f32x4 acc[4][4];
    #pragma unroll
    for (int i = 0; i < 4; ++i)
        #pragma unroll
        for (int j = 0; j < 4; ++j) acc[i][j] = (f32x4){0.f, 0.f, 0.f, 0.f};

    const int c1 = tid;        // chunk ids (16B each); tile = 512 chunks
    const int c2 = 256 + tid;
    const int cb1 = wave * 64;         // wave-uniform LDS chunk base
    const int cb2 = 256 + wave * 64;

    for (int k0 = 0; k0 < K; k0 += 32) {
        const unsigned short* Ab = A + (size_t)bm * K + k0;
        const unsigned short* Bb = Bt + (size_t)bn * K + k0;
        gload_lds16(Ab + (size_t)(c1 >> 2) * K + (c1 & 3) * 8, &As[cb1 * 8]);
        gload_lds16(Ab + (size_t)(c2 >> 2) * K + (c2 & 3) * 8, &As[cb2 * 8]);
        gload_lds16(Bb + (size_t)(c1 >> 2) * K + (c1 & 3) * 8, &Bs[cb1 * 8]);
        gload_lds16(Bb + (size_t)(c2 >> 2) * K + (c2 & 3) * 8, &Bs[cb2 * 8]);
        __syncthreads();

        bf16x8 af[4], bfr[4];
        #pragma unroll
        for (int i = 0; i < 4; ++i)
            af[i] = *reinterpret_cast<const bf16x8*>(&As[(wr * 64 + i * 16 + r) * 32 + kq * 8]);
        #pragma unroll
        for (int j = 0; j < 4; ++j)
            bfr[j] = *reinterpret_cast<const bf16x8*>(&Bs[(wc * 64 + j * 16 + r) * 32 + kq * 8]);
        #pragma unroll
        for (int i = 0; i < 4; ++i)
            #pragma unroll
            for (int j = 0; j < 4; ++j)
                acc[i][j] = __builtin_amdgcn_mfma_f32_16x16x32_bf16(af[i], bfr[j], acc[i][j], 0, 0, 0);
        __syncthreads();
    }

    float* Cf = (float*)C;
    unsigned short* Cb = (unsigned short*)C;
    #pragma unroll
    for (int i = 0; i < 4; ++i) {
        int row0 = bm + wr * 64 + i * 16 + kq * 4;
        #pragma unroll
        for (int j = 0; j < 4; ++j) {
            int col = bn + wc * 64 + j * 16 + r;
            float bs = bias[col];
            #pragma unroll
            for (int rr = 0; rr < 4; ++rr) {
                float val = acc[i][j][rr] + bs;
                size_t off = (size_t)(row0 + rr) * N + col;
                if (OUT_F32) Cf[off] = val;
                else Cb[off] = f2bf(val);
            }
        }
    }
}

extern "C" void kernel_launch(void* const* d_in, const int* in_sizes, int n_in,
                              void* d_out, int out_size, void* d_ws, size_t ws_size,
                              hipStream_t stream) {
    const float* query  = (const float*)d_in[0];
    const float* value  = (const float*)d_in[2];
    const float* w_value = (const float*)d_in[5];
    const float* b_value = (const float*)d_in[6];
    const float* w_off   = (const float*)d_in[7];
    const float* b_off   = (const float*)d_in[8];
    const float* w_attw  = (const float*)d_in[9];
    const float* b_attw  = (const float*)d_in[10];
    const float* w_out   = (const float*)d_in[11];
    const float* b_out   = (const float*)d_in[12];
    float* out = (float*)d_out;

    char* w = (char*)d_ws;
    unsigned short* Vbf   = (unsigned short*)(w);                       // 0..16MB
    unsigned short* WvT   = (unsigned short*)(w + (16ull << 20));       // 16..18
    unsigned short* WoT   = (unsigned short*)(w + (18ull << 20));       // 18..20
    unsigned short* Vproj = (unsigned short*)(w + (20ull << 20));       // 20..36
    unsigned short* S     = (unsigned short*)(w + (36ull << 20));       // 36..52
    float*          Logits= (float*)(w + (36ull << 20));                // shares with S (dead before sample)
    int*            Idx   = (int*)(w + (52ull << 20));                  // 52..54
    float*          C0    = (float*)(w + (54ull << 20));                // 54..56
    float*          C1    = (float*)(w + (56ull << 20));                // 56..58

    // 1. value -> bf16, only the gatherable rows l in [1920,4096) per batch
    cvt_slice<<<4352, 256, 0, stream>>>(value, Vbf);
    // 2. weight transposes -> bf16 (N x K)
    dim3 tb(32, 8);
    transpose_bf16<<<dim3(32, 32), tb, 0, stream>>>(w_value, WvT, 1024, 1024);
    transpose_bf16<<<dim3(32, 32), tb, 0, stream>>>(w_out, WoT, 1024, 1024);
    // 3. off/attw logits GEMM (fp32) + coefficient kernel
    offw_gemm<<<1024, 192, 0, stream>>>(query, w_off, b_off, w_attw, b_attw, Logits);
    coef_kernel<<<2048, 256, 0, stream>>>(Logits, Idx, C0, C1);
    // 4. v = value @ w_value + b_value (bf16 out), rows [1920,4096) per batch
    gemm_bt<false><<<dim3(17, 8, 2), 256, 0, stream>>>(Vbf, WvT, b_value, Vproj, 1920, 4096, 1024, 1024);
    // 5. gather + weighted combine -> s (bf16)
    sample_kernel<<<8192, 256, 0, stream>>>(Vproj, Idx, C0, C1, S);
    // 6. out = s @ w_out + b_out (fp32 out)
    gemm_bt<true><<<dim3(64, 8, 1), 256, 0, stream>>>(S, WoT, b_out, out, 0, 0, 1024, 1024);
}

// Round 3
// 111.376 us; speedup vs baseline: 2.5133x; 1.7354x over previous
//
#include <hip/hip_runtime.h>
#include <hip/hip_bf16.h>

typedef __bf16 bf16x8 __attribute__((ext_vector_type(8)));
typedef float f32x4 __attribute__((ext_vector_type(4)));

static __device__ __forceinline__ unsigned short f2bf(float x) {
    __hip_bfloat16 b = __float2bfloat16(x);
    return __builtin_bit_cast(unsigned short, b);
}
static __device__ __forceinline__ float bf2f(unsigned short u) {
    __hip_bfloat16 b = __builtin_bit_cast(__hip_bfloat16, u);
    return __bfloat162float(b);
}

static __device__ __forceinline__ void gload_lds16(const void* g, void* l) {
    __builtin_amdgcn_global_load_lds(
        (const __attribute__((address_space(1))) void*)g,
        (__attribute__((address_space(3))) void*)l, 16, 0, 0);
}

// ---------------- convert fp32 -> bf16, only rows [1920,4096) per batch ----------------
__global__ __launch_bounds__(256) void cvt_slice(const float* __restrict__ in,
                                                 unsigned short* __restrict__ out) {
    int g = blockIdx.x * 256 + threadIdx.x;      // 2*2176*256 total
    int r4 = g >> 8;                              // sliced row id
    int cpos = g & 255;                           // float4 within row
    int b = r4 / 2176;
    int l = 1920 + (r4 % 2176);
    size_t off4 = (size_t)(b * 4096 + l) * 256 + cpos;
    float4 v = reinterpret_cast<const float4*>(in)[off4];
    ushort4 o;
    o.x = f2bf(v.x); o.y = f2bf(v.y); o.z = f2bf(v.z); o.w = f2bf(v.w);
    reinterpret_cast<ushort4*>(out)[off4] = o;
}

// ---------------- transpose (K x N fp32) -> (N x K bf16) ----------------
__global__ void transpose_bf16(const float* __restrict__ in,
                               unsigned short* __restrict__ out,
                               int K, int N) {
    __shared__ float tile[32][33];
    int k0 = blockIdx.x * 32, n0 = blockIdx.y * 32;
    int tx = threadIdx.x, ty = threadIdx.y;  // (32, 8)
    for (int i = ty; i < 32; i += 8) tile[i][tx] = in[(size_t)(k0 + i) * N + n0 + tx];
    __syncthreads();
    for (int i = ty; i < 32; i += 8)
        out[(size_t)(n0 + i) * K + k0 + tx] = f2bf(tile[tx][i]);
}

// ---- combined off/attw weight: transpose + hi/lo bf16 split: (1024x192) -> 2x (192x1024) ----
__global__ void wsplit_transpose(const float* __restrict__ w_off,
                                 const float* __restrict__ w_attw,
                                 unsigned short* __restrict__ WThi,
                                 unsigned short* __restrict__ WTlo) {
    __shared__ float tile[32][33];
    int k0 = blockIdx.x * 32;   // 32
    int n0 = blockIdx.y * 32;   // 6
    int tx = threadIdx.x, ty = threadIdx.y;  // (32, 8)
    for (int i = ty; i < 32; i += 8) {
        int k = k0 + i, n = n0 + tx;
        float v = (n < 128) ? w_off[(size_t)k * 128 + n] : w_attw[(size_t)k * 64 + (n - 128)];
        tile[i][tx] = v;
    }
    __syncthreads();
    for (int i = ty; i < 32; i += 8) {
        int n = n0 + i, k = k0 + tx;
        float v = tile[tx][i];
        unsigned short hi = f2bf(v);
        unsigned short lo = f2bf(v - bf2f(hi));
        WThi[(size_t)n * 1024 + k] = hi;
        WTlo[(size_t)n * 1024 + k] = lo;
    }
}

// ---------------- off/attw logits via split-bf16 MFMA ----------------
// part[sk][8192][192] fp32 partials; logits = sum_sk part + bias (done in coef_kernel).
// Block tile: M=128, N=64, BK=32, split-K 4 (K=256 each). 4 waves in 2x2.
__global__ __launch_bounds__(256, 3) void offw_mfma(
    const float* __restrict__ query,          // 8192 x 1024 fp32
    const unsigned short* __restrict__ WThi,  // 192 x 1024 bf16
    const unsigned short* __restrict__ WTlo,
    float* __restrict__ part) {
    __shared__ unsigned short Ahi[128 * 32], Alo[128 * 32];
    __shared__ unsigned short Bhi[64 * 32], Blo[64 * 32];
    const int tid = threadIdx.x;
    const int lane = tid & 63, wave = tid >> 6;
    const int bm = blockIdx.x * 128;
    const int bn = blockIdx.y * 64;
    const int sk = blockIdx.z;
    const int wr = wave >> 1, wc = wave & 1;
    const int r = lane & 15, kq = lane >> 4;

    f32x4 acc[4][2];
    #pragma unroll
    for (int i = 0; i < 4; ++i)
        #pragma unroll
        for (int j = 0; j < 2; ++j) acc[i][j] = (f32x4){0.f, 0.f, 0.f, 0.f};

    // A staging: thread -> (row, 16-k half)
    const int arow = tid >> 1;
    const int akh = (tid & 1) * 16;
    // B staging: thread -> (plane, 16-k chunk pair)
    const int bplane = tid >> 7;               // 0=hi, 1=lo
    const int bc = (tid & 127) * 2;            // even chunk id
    const int brow = bc >> 2;                  // 0..63
    const int bko = (bc & 3) * 8;              // 0 or 16

    const unsigned short* bsrc = bplane ? WTlo : WThi;
    unsigned short* bdst = bplane ? Blo : Bhi;

    for (int k0 = sk * 256; k0 < sk * 256 + 256; k0 += 32) {
        // --- stage A: read 16 fp32 of query, split hi/lo, write LDS ---
        const float* qp = query + (size_t)(bm + arow) * 1024 + k0 + akh;
        float4 qf0 = reinterpret_cast<const float4*>(qp)[0];
        float4 qf1 = reinterpret_cast<const float4*>(qp)[1];
        float4 qf2 = reinterpret_cast<const float4*>(qp)[2];
        float4 qf3 = reinterpret_cast<const float4*>(qp)[3];
        unsigned int hw[8], lw[8];
        {
            float4 qf[4] = {qf0, qf1, qf2, qf3};
            #pragma unroll
            for (int t = 0; t < 4; ++t) {
                float e0 = qf[t].x, e1 = qf[t].y, e2 = qf[t].z, e3 = qf[t].w;
                unsigned short h0 = f2bf(e0), h1 = f2bf(e1), h2 = f2bf(e2), h3 = f2bf(e3);
                unsigned short l0 = f2bf(e0 - bf2f(h0)), l1 = f2bf(e1 - bf2f(h1));
                unsigned short l2 = f2bf(e2 - bf2f(h2)), l3 = f2bf(e3 - bf2f(h3));
                hw[t * 2] = (unsigned int)h0 | ((unsigned int)h1 << 16);
                hw[t * 2 + 1] = (unsigned int)h2 | ((unsigned int)h3 << 16);
                lw[t * 2] = (unsigned int)l0 | ((unsigned int)l1 << 16);
                lw[t * 2 + 1] = (unsigned int)l2 | ((unsigned int)l3 << 16);
            }
        }
        *reinterpret_cast<uint4*>(&Ahi[arow * 32 + akh]) = (uint4){hw[0], hw[1], hw[2], hw[3]};
        *reinterpret_cast<uint4*>(&Ahi[arow * 32 + akh + 8]) = (uint4){hw[4], hw[5], hw[6], hw[7]};
        *reinterpret_cast<uint4*>(&Alo[arow * 32 + akh]) = (uint4){lw[0], lw[1], lw[2], lw[3]};
        *reinterpret_cast<uint4*>(&Alo[arow * 32 + akh + 8]) = (uint4){lw[4], lw[5], lw[6], lw[7]};
        // --- stage B: copy 16 bf16 of the pre-split weight plane ---
        {
            const unsigned short* bp = bsrc + (size_t)(bn + brow) * 1024 + k0 + bko;
            uint4 b0 = *reinterpret_cast<const uint4*>(bp);
            uint4 b1 = *reinterpret_cast<const uint4*>(bp + 8);
            *reinterpret_cast<uint4*>(&bdst[brow * 32 + bko]) = b0;
            *reinterpret_cast<uint4*>(&bdst[brow * 32 + bko + 8]) = b1;
        }
        __syncthreads();

        bf16x8 ah[4], al[4], bh[2], bl[2];
        #pragma unroll
        for (int i = 0; i < 4; ++i) {
            int ro = (wr * 64 + i * 16 + r) * 32 + kq * 8;
            ah[i] = *reinterpret_cast<const bf16x8*>(&Ahi[ro]);
            al[i] = *reinterpret_cast<const bf16x8*>(&Alo[ro]);
        }
        #pragma unroll
        for (int j = 0; j < 2; ++j) {
            int ro = (wc * 32 + j * 16 + r) * 32 + kq * 8;
            bh[j] = *reinterpret_cast<const bf16x8*>(&Bhi[ro]);
            bl[j] = *reinterpret_cast<const bf16x8*>(&Blo[ro]);
        }
        #pragma unroll
        for (int i = 0; i < 4; ++i)
            #pragma unroll
            for (int j = 0; j < 2; ++j) {
                acc[i][j] = __builtin_amdgcn_mfma_f32_16x16x32_bf16(ah[i], bh[j], acc[i][j], 0, 0, 0);
                acc[i][j] = __builtin_amdgcn_mfma_f32_16x16x32_bf16(ah[i], bl[j], acc[i][j], 0, 0, 0);
                acc[i][j] = __builtin_amdgcn_mfma_f32_16x16x32_bf16(al[i], bh[j], acc[i][j], 0, 0, 0);
            }
        __syncthreads();
    }

    float* P = part + (size_t)sk * 8192 * 192;
    #pragma unroll
    for (int i = 0; i < 4; ++i) {
        int row0 = bm + wr * 64 + i * 16 + kq * 4;
        #pragma unroll
        for (int j = 0; j < 2; ++j) {
            int col = bn + wc * 32 + j * 16 + r;
            #pragma unroll
            for (int rr = 0; rr < 4; ++rr)
                P[(size_t)(row0 + rr) * 192 + col] = acc[i][j][rr];
        }
    }
}

// ---------------- softmax + grid-sample coefficients (sums split-K partials) ----------------
__global__ __launch_bounds__(256) void coef_kernel(
    const float* __restrict__ part, const float* __restrict__ b_off,
    const float* __restrict__ b_attw, int* __restrict__ idx_out,
    float* __restrict__ c0_out, float* __restrict__ c1_out) {
    const size_t SK = (size_t)8192 * 192;
    int g = blockIdx.x * 256 + threadIdx.x;   // 8192*64
    int n = g >> 6, e = g & 63;
    int l = n & 4095;
    int h = e >> 2, p = e & 3;
    const float* Pn = part + (size_t)n * 192;
    auto L = [&](int c) {
        float s = (c < 128) ? b_off[c] : b_attw[c - 128];
        return s + Pn[c] + Pn[c + SK] + Pn[c + 2 * SK] + Pn[c + 3 * SK];
    };
    float l0 = L(128 + h * 4 + 0), l1 = L(128 + h * 4 + 1);
    float l2 = L(128 + h * 4 + 2), l3 = L(128 + h * 4 + 3);
    float mx = fmaxf(fmaxf(l0, l1), fmaxf(l2, l3));
    float e0 = expf(l0 - mx), e1 = expf(l1 - mx), e2 = expf(l2 - mx), e3 = expf(l3 - mx);
    float esum = e0 + e1 + e2 + e3;
    float aw = ((p == 0) ? e0 : (p == 1) ? e1 : (p == 2) ? e2 : e3) / esum;
    float o0 = L(h * 8 + p * 2), o1 = L(h * 8 + p * 2 + 1);
    float sx = fminf(fmaxf(o0, 0.f), 1.f);
    float ry = (float)l / 4095.0f;
    float sy = fminf(fmaxf(ry + o1, 0.f), 1.f);
    float ix = ((sx + 1.f) * 4096.f - 1.f) * 0.5f;
    float iy = sy * 0.5f;
    float x0f = floorf(ix);
    float fx = ix - x0f;
    int x0 = (int)x0f;
    int x1 = x0 + 1;
    float m0 = (x0 >= 0 && x0 < 4096) ? 1.f : 0.f;
    float m1 = (x1 >= 0 && x1 < 4096) ? 1.f : 0.f;
    float y0f = floorf(iy);
    float fy = iy - y0f;
    float hy = ((y0f == 0.f) ? (1.f - fy) : 0.f) + ((y0f == -1.f) ? fy : 0.f);
    float c0 = aw * (1.f - fx) * m0 * hy;
    float c1 = aw * fx * m1 * hy;
    int x0c = x0 < 0 ? 0 : (x0 > 4095 ? 4095 : x0);
    idx_out[g] = x0c;
    c0_out[g] = c0;
    c1_out[g] = c1;
}

// ---------------- gather + weighted combine ----------------
__global__ __launch_bounds__(256) void sample_kernel(
    const unsigned short* __restrict__ vproj,  // (B*L, 1024) bf16
    const int* __restrict__ idx, const float* __restrict__ c0a,
    const float* __restrict__ c1a, unsigned short* __restrict__ s_out) {
    const int n = blockIdx.x;
    const int tid = threadIdx.x;
    __shared__ int sIdx[64];
    __shared__ float sC0[64], sC1[64];
    if (tid < 64) {
        int o = n * 64 + tid;
        sIdx[tid] = idx[o];
        sC0[tid] = c0a[o];
        sC1[tid] = c1a[o];
    }
    __syncthreads();
    const int d = tid * 4;
    const int h = tid >> 4;
    const size_t vb = (size_t)(n >> 12) * 4096 * 1024;
    float a0 = 0.f, a1 = 0.f, a2 = 0.f, a3 = 0.f;
    #pragma unroll
    for (int p = 0; p < 4; ++p) {
        int e = h * 4 + p;
        int x0 = sIdx[e];
        float c0 = sC0[e], c1 = sC1[e];
        int x1 = (x0 + 1 > 4095) ? 4095 : x0 + 1;
        ushort4 v0 = *reinterpret_cast<const ushort4*>(vproj + vb + (size_t)x0 * 1024 + d);
        ushort4 v1 = *reinterpret_cast<const ushort4*>(vproj + vb + (size_t)x1 * 1024 + d);
        a0 += c0 * bf2f(v0.x) + c1 * bf2f(v1.x);
        a1 += c0 * bf2f(v0.y) + c1 * bf2f(v1.y);
        a2 += c0 * bf2f(v0.z) + c1 * bf2f(v1.z);
        a3 += c0 * bf2f(v0.w) + c1 * bf2f(v1.w);
    }
    ushort4 o;
    o.x = f2bf(a0); o.y = f2bf(a1); o.z = f2bf(a2); o.w = f2bf(a3);
    *reinterpret_cast<ushort4*>(s_out + (size_t)n * 1024 + d) = o;
}

// ---------------- bf16 MFMA GEMM: C = A(rows x K) * Bt(NxK)^T + bias ----------------
template <bool OUT_F32>
__global__ __launch_bounds__(256, 2) void gemm_bt(
    const unsigned short* __restrict__ A,   // bf16, rows x K
    const unsigned short* __restrict__ Bt,  // N x K bf16
    const float* __restrict__ bias,         // N
    void* __restrict__ C, int rowoff, int zstride, int N, int K) {
    __shared__ unsigned short As[128 * 32];  // [m][k]
    __shared__ unsigned short Bs[128 * 32];  // [n][k]
    const int tid = threadIdx.x;
    const int lane = tid & 63;
    const int wave = tid >> 6;
    const int bm = rowoff + blockIdx.z * zstride + blockIdx.x * 128;
    const int bn = blockIdx.y * 128;
    const int wr = wave >> 1;  // 0..1
    const int wc = wave & 1;   // 0..1
    const int r = lane & 15;
    const int kq = lane >> 4;  // 0..3

    f32x4 acc[4][4];
    #pragma unroll
    for (int i = 0; i < 4; ++i)
        #pragma unroll
        for (int j = 0; j < 4; ++j) acc[i][j] = (f32x4){0.f, 0.f, 0.f, 0.f};

    const int c1 = tid;        // chunk ids (16B each); tile = 512 chunks
    const int c2 = 256 + tid;
    const int cb1 = wave * 64;         // wave-uniform LDS chunk base
    const int cb2 = 256 + wave * 64;

    for (int k0 = 0; k0 < K; k0 += 32) {
        const unsigned short* Ab = A + (size_t)bm * K + k0;
        const unsigned short* Bb = Bt + (size_t)bn * K + k0;
        gload_lds16(Ab + (size_t)(c1 >> 2) * K + (c1 & 3) * 8, &As[cb1 * 8]);
        gload_lds16(Ab + (size_t)(c2 >> 2) * K + (c2 & 3) * 8, &As[cb2 * 8]);
        gload_lds16(Bb + (size_t)(c1 >> 2) * K + (c1 & 3) * 8, &Bs[cb1 * 8]);
        gload_lds16(Bb + (size_t)(c2 >> 2) * K + (c2 & 3) * 8, &Bs[cb2 * 8]);
        __syncthreads();

        bf16x8 af[4], bfr[4];
        #pragma unroll
        for (int i = 0; i < 4; ++i)
            af[i] = *reinterpret_cast<const bf16x8*>(&As[(wr * 64 + i * 16 + r) * 32 + kq * 8]);
        #pragma unroll
        for (int j = 0; j < 4; ++j)
            bfr[j] = *reinterpret_cast<const bf16x8*>(&Bs[(wc * 64 + j * 16 + r) * 32 + kq * 8]);
        #pragma unroll
        for (int i = 0; i < 4; ++i)
            #pragma unroll
            for (int j = 0; j < 4; ++j)
                acc[i][j] = __builtin_amdgcn_mfma_f32_16x16x32_bf16(af[i], bfr[j], acc[i][j], 0, 0, 0);
        __syncthreads();
    }

    float* Cf = (float*)C;
    unsigned short* Cb = (unsigned short*)C;
    #pragma unroll
    for (int i = 0; i < 4; ++i) {
        int row0 = bm + wr * 64 + i * 16 + kq * 4;
        #pragma unroll
        for (int j = 0; j < 4; ++j) {
            int col = bn + wc * 64 + j * 16 + r;
            float bs = bias[col];
            #pragma unroll
            for (int rr = 0; rr < 4; ++rr) {
                float val = acc[i][j][rr] + bs;
                size_t off = (size_t)(row0 + rr) * N + col;
                if (OUT_F32) Cf[off] = val;
                else Cb[off] = f2bf(val);
            }
        }
    }
}

extern "C" void kernel_launch(void* const* d_in, const int* in_sizes, int n_in,
                              void* d_out, int out_size, void* d_ws, size_t ws_size,
                              hipStream_t stream) {
    const float* query  = (const float*)d_in[0];
    const float* value  = (const float*)d_in[2];
    const float* w_value = (const float*)d_in[5];
    const float* b_value = (const float*)d_in[6];
    const float* w_off   = (const float*)d_in[7];
    const float* b_off   = (const float*)d_in[8];
    const float* w_attw  = (const float*)d_in[9];
    const float* b_attw  = (const float*)d_in[10];
    const float* w_out   = (const float*)d_in[11];
    const float* b_out   = (const float*)d_in[12];
    float* out = (float*)d_out;

    char* w = (char*)d_ws;
    unsigned short* Vbf   = (unsigned short*)(w);                       // 0..16MB   (cvt -> gemm1)
    unsigned short* WvT   = (unsigned short*)(w + (16ull << 20));       // 16..18    (-> gemm1)
    unsigned short* WoT   = (unsigned short*)(w + (18ull << 20));       // 18..20    (-> gemm2)
    float*          Part  = (float*)(w + (20ull << 20));                // 20..45.2  (offw -> coef); dead before Vproj/S written
    unsigned short* Vproj = (unsigned short*)(w + (20ull << 20));       // 20..36    (gemm1 -> sample)
    unsigned short* S     = (unsigned short*)(w + (36ull << 20));       // 36..52    (sample -> gemm2)
    unsigned short* WThi  = (unsigned short*)(w + (46ull << 20));       // 46..46.4  (wsplit -> offw); inside S region, dead by then
    unsigned short* WTlo  = (unsigned short*)(w + (47ull << 20));       // 47..47.4
    int*            Idx   = (int*)(w + (52ull << 20));                  // 52..54
    float*          C0    = (float*)(w + (54ull << 20));                // 54..56
    float*          C1    = (float*)(w + (56ull << 20));                // 56..58

    // 1. value -> bf16, only the gatherable rows l in [1920,4096) per batch
    cvt_slice<<<4352, 256, 0, stream>>>(value, Vbf);
    // 2. weight transposes -> bf16 (N x K); off/attw weights hi/lo split
    dim3 tb(32, 8);
    transpose_bf16<<<dim3(32, 32), tb, 0, stream>>>(w_value, WvT, 1024, 1024);
    transpose_bf16<<<dim3(32, 32), tb, 0, stream>>>(w_out, WoT, 1024, 1024);
    wsplit_transpose<<<dim3(32, 6), tb, 0, stream>>>(w_off, w_attw, WThi, WTlo);
    // 3. off/attw logits via split-bf16 MFMA (split-K partials) + coefficient kernel
    offw_mfma<<<dim3(64, 3, 4), 256, 0, stream>>>(query, WThi, WTlo, Part);
    coef_kernel<<<2048, 256, 0, stream>>>(Part, b_off, b_attw, Idx, C0, C1);
    // 4. v = value @ w_value + b_value (bf16 out), rows [1920,4096) per batch
    gemm_bt<false><<<dim3(17, 8, 2), 256, 0, stream>>>(Vbf, WvT, b_value, Vproj, 1920, 4096, 1024, 1024);
    // 5. gather + weighted combine -> s (bf16)
    sample_kernel<<<8192, 256, 0, stream>>>(Vproj, Idx, C0, C1, S);
    // 6. out = s @ w_out + b_out (fp32 out)
    gemm_bt<true><<<dim3(64, 8, 1), 256, 0, stream>>>(S, WoT, b_out, out, 0, 0, 1024, 1024);
}

// Round 5
// 108.634 us; speedup vs baseline: 2.5767x; 1.0252x over previous
//
#include <hip/hip_runtime.h>
#include <hip/hip_bf16.h>

typedef __bf16 bf16x8 __attribute__((ext_vector_type(8)));
typedef float f32x4 __attribute__((ext_vector_type(4)));

static __device__ __forceinline__ unsigned short f2bf(float x) {
    __hip_bfloat16 b = __float2bfloat16(x);
    return __builtin_bit_cast(unsigned short, b);
}
static __device__ __forceinline__ float bf2f(unsigned short u) {
    __hip_bfloat16 b = __builtin_bit_cast(__hip_bfloat16, u);
    return __bfloat162float(b);
}

static __device__ __forceinline__ void gload_lds16(const void* g, void* l) {
    __builtin_amdgcn_global_load_lds(
        (const __attribute__((address_space(1))) void*)g,
        (__attribute__((address_space(3))) void*)l, 16, 0, 0);
}

// ---------------- convert fp32 -> bf16, only rows [1920,4096) per batch ----------------
__global__ __launch_bounds__(256) void cvt_slice(const float* __restrict__ in,
                                                 unsigned short* __restrict__ out) {
    int g = blockIdx.x * 256 + threadIdx.x;      // 2*2176*256 total
    int r4 = g >> 8;                              // sliced row id
    int cpos = g & 255;                           // float4 within row
    int b = r4 / 2176;
    int l = 1920 + (r4 % 2176);
    size_t off4 = (size_t)(b * 4096 + l) * 256 + cpos;
    float4 v = reinterpret_cast<const float4*>(in)[off4];
    ushort4 o;
    o.x = f2bf(v.x); o.y = f2bf(v.y); o.z = f2bf(v.z); o.w = f2bf(v.w);
    reinterpret_cast<ushort4*>(out)[off4] = o;
}

// ---------------- transpose (K x N fp32) -> (N x K bf16) ----------------
__global__ void transpose_bf16(const float* __restrict__ in,
                               unsigned short* __restrict__ out,
                               int K, int N) {
    __shared__ float tile[32][33];
    int k0 = blockIdx.x * 32, n0 = blockIdx.y * 32;
    int tx = threadIdx.x, ty = threadIdx.y;  // (32, 8)
    for (int i = ty; i < 32; i += 8) tile[i][tx] = in[(size_t)(k0 + i) * N + n0 + tx];
    __syncthreads();
    for (int i = ty; i < 32; i += 8)
        out[(size_t)(n0 + i) * K + k0 + tx] = f2bf(tile[tx][i]);
}

// ---- combined off/attw weight: transpose + hi/lo bf16 split: (1024x192) -> 2x (192x1024) ----
__global__ void wsplit_transpose(const float* __restrict__ w_off,
                                 const float* __restrict__ w_attw,
                                 unsigned short* __restrict__ WThi,
                                 unsigned short* __restrict__ WTlo) {
    __shared__ float tile[32][33];
    int k0 = blockIdx.x * 32;   // 32
    int n0 = blockIdx.y * 32;   // 6
    int tx = threadIdx.x, ty = threadIdx.y;  // (32, 8)
    for (int i = ty; i < 32; i += 8) {
        int k = k0 + i, n = n0 + tx;
        float v = (n < 128) ? w_off[(size_t)k * 128 + n] : w_attw[(size_t)k * 64 + (n - 128)];
        tile[i][tx] = v;
    }
    __syncthreads();
    for (int i = ty; i < 32; i += 8) {
        int n = n0 + i, k = k0 + tx;
        float v = tile[tx][i];
        unsigned short hi = f2bf(v);
        unsigned short lo = f2bf(v - bf2f(hi));
        WThi[(size_t)n * 1024 + k] = hi;
        WTlo[(size_t)n * 1024 + k] = lo;
    }
}

// ---------------- off/attw logits via split-bf16 MFMA ----------------
// BM=128, BN=192 (whole N in one block), BK=32, split-K 4. 512 threads = 8 waves (2x4).
// part[sk][8192][192] fp32 partials; logits summed (+bias) in sample_coef.
__global__ __launch_bounds__(512, 1) void offw_mfma(
    const float* __restrict__ query,          // 8192 x 1024 fp32
    const unsigned short* __restrict__ WThi,  // 192 x 1024 bf16
    const unsigned short* __restrict__ WTlo,
    float* __restrict__ part) {
    __shared__ unsigned short Ahi[128 * 32], Alo[128 * 32];
    __shared__ unsigned short Bs2[2 * 192 * 32];   // [plane][row][k] chunk-linear
    const int tid = threadIdx.x;
    const int lane = tid & 63, wave = tid >> 6;
    const int bm = blockIdx.x * 128;
    const int sk = blockIdx.y;
    const int wr = wave >> 2;        // 0..1
    const int wc = wave & 3;         // 0..3
    const int r = lane & 15, kq = lane >> 4;

    f32x4 acc[4][3];
    #pragma unroll
    for (int i = 0; i < 4; ++i)
        #pragma unroll
        for (int j = 0; j < 3; ++j) acc[i][j] = (f32x4){0.f, 0.f, 0.f, 0.f};

    // A staging: thread -> (row, 8-float chunk)
    const int arow = tid >> 2;
    const int apos = (tid & 3) * 8;

    for (int k0 = sk * 256; k0 < sk * 256 + 256; k0 += 32) {
        // --- stage A: read 8 fp32 of query, split hi/lo, ds_write ---
        const float* qp = query + (size_t)(bm + arow) * 1024 + k0 + apos;
        float4 qa = reinterpret_cast<const float4*>(qp)[0];
        float4 qb = reinterpret_cast<const float4*>(qp)[1];
        unsigned int hw[4], lw[4];
        {
            float4 qf[2] = {qa, qb};
            #pragma unroll
            for (int t = 0; t < 2; ++t) {
                float e0 = qf[t].x, e1 = qf[t].y, e2 = qf[t].z, e3 = qf[t].w;
                unsigned short h0 = f2bf(e0), h1 = f2bf(e1), h2 = f2bf(e2), h3 = f2bf(e3);
                unsigned short l0 = f2bf(e0 - bf2f(h0)), l1 = f2bf(e1 - bf2f(h1));
                unsigned short l2 = f2bf(e2 - bf2f(h2)), l3 = f2bf(e3 - bf2f(h3));
                hw[t * 2] = (unsigned int)h0 | ((unsigned int)h1 << 16);
                hw[t * 2 + 1] = (unsigned int)h2 | ((unsigned int)h3 << 16);
                lw[t * 2] = (unsigned int)l0 | ((unsigned int)l1 << 16);
                lw[t * 2 + 1] = (unsigned int)l2 | ((unsigned int)l3 << 16);
            }
        }
        *reinterpret_cast<uint4*>(&Ahi[arow * 32 + apos]) = (uint4){hw[0], hw[1], hw[2], hw[3]};
        *reinterpret_cast<uint4*>(&Alo[arow * 32 + apos]) = (uint4){lw[0], lw[1], lw[2], lw[3]};
        // --- stage B via global_load_lds: 2 planes x 192 rows x 4 chunks = 1536 chunks ---
        #pragma unroll
        for (int t = 0; t < 3; ++t) {
            int c = tid + 512 * t;                 // 0..1535; c&63 == lane (512t % 64 == 0)
            int plane = (c >= 768);
            int cp = c - 768 * plane;              // in-plane chunk
            const unsigned short* src = (plane ? WTlo : WThi)
                + (size_t)(cp >> 2) * 1024 + k0 + (cp & 3) * 8;
            gload_lds16(src, &Bs2[(size_t)(c & ~63) * 8]);  // wave-uniform base + lane*16B
        }
        __syncthreads();

        bf16x8 ah[4], al[4], bh[3], bl[3];
        #pragma unroll
        for (int i = 0; i < 4; ++i) {
            int ro = (wr * 64 + i * 16 + r) * 32 + kq * 8;
            ah[i] = *reinterpret_cast<const bf16x8*>(&Ahi[ro]);
            al[i] = *reinterpret_cast<const bf16x8*>(&Alo[ro]);
        }
        #pragma unroll
        for (int j = 0; j < 3; ++j) {
            int ro = (wc * 48 + j * 16 + r) * 32 + kq * 8;
            bh[j] = *reinterpret_cast<const bf16x8*>(&Bs2[ro]);
            bl[j] = *reinterpret_cast<const bf16x8*>(&Bs2[192 * 32 + ro]);
        }
        #pragma unroll
        for (int i = 0; i < 4; ++i)
            #pragma unroll
            for (int j = 0; j < 3; ++j) {
                acc[i][j] = __builtin_amdgcn_mfma_f32_16x16x32_bf16(ah[i], bh[j], acc[i][j], 0, 0, 0);
                acc[i][j] = __builtin_amdgcn_mfma_f32_16x16x32_bf16(ah[i], bl[j], acc[i][j], 0, 0, 0);
                acc[i][j] = __builtin_amdgcn_mfma_f32_16x16x32_bf16(al[i], bh[j], acc[i][j], 0, 0, 0);
            }
        __syncthreads();
    }

    float* P = part + (size_t)sk * 8192 * 192;
    #pragma unroll
    for (int i = 0; i < 4; ++i) {
        int row0 = bm + wr * 64 + i * 16 + kq * 4;
        #pragma unroll
        for (int j = 0; j < 3; ++j) {
            int col = wc * 48 + j * 16 + r;
            #pragma unroll
            for (int rr = 0; rr < 4; ++rr)
                P[(size_t)(row0 + rr) * 192 + col] = acc[i][j][rr];
        }
    }
}

// ------- fused: logits sum + softmax + grid-sample coefficients + gather/combine -------
__global__ __launch_bounds__(256) void sample_coef(
    const float* __restrict__ part, const float* __restrict__ b_off,
    const float* __restrict__ b_attw, const unsigned short* __restrict__ vproj,
    unsigned short* __restrict__ s_out) {
    const int n = blockIdx.x;     // 0..8191
    const int tid = threadIdx.x;
    const int l = n & 4095;
    __shared__ float Ls[192];
    __shared__ int sIdx[64];
    __shared__ float sC0[64], sC1[64];
    if (tid < 192) {
        const size_t SK = (size_t)8192 * 192;
        const float* Pn = part + (size_t)n * 192 + tid;
        float s = (tid < 128) ? b_off[tid] : b_attw[tid - 128];
        Ls[tid] = s + Pn[0] + Pn[SK] + Pn[2 * SK] + Pn[3 * SK];
    }
    __syncthreads();
    if (tid < 64) {
        int h = tid >> 2, p = tid & 3;
        float l0 = Ls[128 + h * 4 + 0], l1 = Ls[128 + h * 4 + 1];
        float l2 = Ls[128 + h * 4 + 2], l3 = Ls[128 + h * 4 + 3];
        float mx = fmaxf(fmaxf(l0, l1), fmaxf(l2, l3));
        float e0 = expf(l0 - mx), e1 = expf(l1 - mx), e2 = expf(l2 - mx), e3 = expf(l3 - mx);
        float esum = e0 + e1 + e2 + e3;
        float aw = ((p == 0) ? e0 : (p == 1) ? e1 : (p == 2) ? e2 : e3) / esum;
        float o0 = Ls[h * 8 + p * 2], o1 = Ls[h * 8 + p * 2 + 1];
        float sx = fminf(fmaxf(o0, 0.f), 1.f);
        float ry = (float)l / 4095.0f;
        float sy = fminf(fmaxf(ry + o1, 0.f), 1.f);
        float ix = ((sx + 1.f) * 4096.f - 1.f) * 0.5f;
        float iy = sy * 0.5f;
        float x0f = floorf(ix);
        float fx = ix - x0f;
        int x0 = (int)x0f;
        int x1 = x0 + 1;
        float m0 = (x0 >= 0 && x0 < 4096) ? 1.f : 0.f;
        float m1 = (x1 >= 0 && x1 < 4096) ? 1.f : 0.f;
        float y0f = floorf(iy);
        float fy = iy - y0f;
        float hy = ((y0f == 0.f) ? (1.f - fy) : 0.f) + ((y0f == -1.f) ? fy : 0.f);
        sC0[tid] = aw * (1.f - fx) * m0 * hy;
        sC1[tid] = aw * fx * m1 * hy;
        sIdx[tid] = x0 < 0 ? 0 : (x0 > 4095 ? 4095 : x0);
    }
    __syncthreads();
    const int d = tid * 4;
    const int h = tid >> 4;
    const size_t vb = (size_t)(n >> 12) * 4096 * 1024;
    float a0 = 0.f, a1 = 0.f, a2 = 0.f, a3 = 0.f;
    #pragma unroll
    for (int p = 0; p < 4; ++p) {
        int e = h * 4 + p;
        int x0 = sIdx[e];
        float c0 = sC0[e], c1 = sC1[e];
        int x1 = (x0 + 1 > 4095) ? 4095 : x0 + 1;
        ushort4 v0 = *reinterpret_cast<const ushort4*>(vproj + vb + (size_t)x0 * 1024 + d);
        ushort4 v1 = *reinterpret_cast<const ushort4*>(vproj + vb + (size_t)x1 * 1024 + d);
        a0 += c0 * bf2f(v0.x) + c1 * bf2f(v1.x);
        a1 += c0 * bf2f(v0.y) + c1 * bf2f(v1.y);
        a2 += c0 * bf2f(v0.z) + c1 * bf2f(v1.z);
        a3 += c0 * bf2f(v0.w) + c1 * bf2f(v1.w);
    }
    ushort4 o;
    o.x = f2bf(a0); o.y = f2bf(a1); o.z = f2bf(a2); o.w = f2bf(a3);
    *reinterpret_cast<ushort4*>(s_out + (size_t)n * 1024 + d) = o;
}

// ---------------- bf16 MFMA GEMM: C = A(rows x K) * Bt(NxK)^T + bias ----------------
template <bool OUT_F32>
__global__ __launch_bounds__(256, 2) void gemm_bt(
    const unsigned short* __restrict__ A,   // bf16, rows x K
    const unsigned short* __restrict__ Bt,  // N x K bf16
    const float* __restrict__ bias,         // N
    void* __restrict__ C, int rowoff, int zstride, int N, int K) {
    __shared__ unsigned short As[128 * 32];  // [m][k]
    __shared__ unsigned short Bs[128 * 32];  // [n][k]
    const int tid = threadIdx.x;
    const int lane = tid & 63;
    const int wave = tid >> 6;
    const int bm = rowoff + blockIdx.z * zstride + blockIdx.x * 128;
    const int bn = blockIdx.y * 128;
    const int wr = wave >> 1;  // 0..1
    const int wc = wave & 1;   // 0..1
    const int r = lane & 15;
    const int kq = lane >> 4;  // 0..3

    f32x4 acc[4][4];
    #pragma unroll
    for (int i = 0; i < 4; ++i)
        #pragma unroll
        for (int j = 0; j < 4; ++j) acc[i][j] = (f32x4){0.f, 0.f, 0.f, 0.f};

    const int c1 = tid;        // chunk ids (16B each); tile = 512 chunks
    const int c2 = 256 + tid;
    const int cb1 = wave * 64;         // wave-uniform LDS chunk base
    const int cb2 = 256 + wave * 64;

    for (int k0 = 0; k0 < K; k0 += 32) {
        const unsigned short* Ab = A + (size_t)bm * K + k0;
        const unsigned short* Bb = Bt + (size_t)bn * K + k0;
        gload_lds16(Ab + (size_t)(c1 >> 2) * K + (c1 & 3) * 8, &As[cb1 * 8]);
        gload_lds16(Ab + (size_t)(c2 >> 2) * K + (c2 & 3) * 8, &As[cb2 * 8]);
        gload_lds16(Bb + (size_t)(c1 >> 2) * K + (c1 & 3) * 8, &Bs[cb1 * 8]);
        gload_lds16(Bb + (size_t)(c2 >> 2) * K + (c2 & 3) * 8, &Bs[cb2 * 8]);
        __syncthreads();

        bf16x8 af[4], bfr[4];
        #pragma unroll
        for (int i = 0; i < 4; ++i)
            af[i] = *reinterpret_cast<const bf16x8*>(&As[(wr * 64 + i * 16 + r) * 32 + kq * 8]);
        #pragma unroll
        for (int j = 0; j < 4; ++j)
            bfr[j] = *reinterpret_cast<const bf16x8*>(&Bs[(wc * 64 + j * 16 + r) * 32 + kq * 8]);
        #pragma unroll
        for (int i = 0; i < 4; ++i)
            #pragma unroll
            for (int j = 0; j < 4; ++j)
                acc[i][j] = __builtin_amdgcn_mfma_f32_16x16x32_bf16(af[i], bfr[j], acc[i][j], 0, 0, 0);
        __syncthreads();
    }

    float* Cf = (float*)C;
    unsigned short* Cb = (unsigned short*)C;
    #pragma unroll
    for (int i = 0; i < 4; ++i) {
        int row0 = bm + wr * 64 + i * 16 + kq * 4;
        #pragma unroll
        for (int j = 0; j < 4; ++j) {
            int col = bn + wc * 64 + j * 16 + r;
            float bs = bias[col];
            #pragma unroll
            for (int rr = 0; rr < 4; ++rr) {
                float val = acc[i][j][rr] + bs;
                size_t off = (size_t)(row0 + rr) * N + col;
                if (OUT_F32) Cf[off] = val;
                else Cb[off] = f2bf(val);
            }
        }
    }
}

extern "C" void kernel_launch(void* const* d_in, const int* in_sizes, int n_in,
                              void* d_out, int out_size, void* d_ws, size_t ws_size,
                              hipStream_t stream) {
    const float* query  = (const float*)d_in[0];
    const float* value  = (const float*)d_in[2];
    const float* w_value = (const float*)d_in[5];
    const float* b_value = (const float*)d_in[6];
    const float* w_off   = (const float*)d_in[7];
    const float* b_off   = (const float*)d_in[8];
    const float* w_attw  = (const float*)d_in[9];
    const float* b_attw  = (const float*)d_in[10];
    const float* w_out   = (const float*)d_in[11];
    const float* b_out   = (const float*)d_in[12];
    float* out = (float*)d_out;

    char* w = (char*)d_ws;
    unsigned short* Vbf   = (unsigned short*)(w);                       // 0..16MB
    unsigned short* WvT   = (unsigned short*)(w + (16ull << 20));       // 16..18
    unsigned short* WoT   = (unsigned short*)(w + (18ull << 20));       // 18..20
    unsigned short* Vproj = (unsigned short*)(w + (20ull << 20));       // 20..36
    unsigned short* S     = (unsigned short*)(w + (36ull << 20));       // 36..52
    unsigned short* WThi  = (unsigned short*)(w + (53ull << 20));       // 53..53.4
    unsigned short* WTlo  = (unsigned short*)(w + (54ull << 20));       // 54..54.4
    float*          Part  = (float*)(w + (56ull << 20));                // 56..81.2
    // all regions disjoint; no lifetime aliasing.

    // 1. value -> bf16, only the gatherable rows l in [1920,4096) per batch
    cvt_slice<<<4352, 256, 0, stream>>>(value, Vbf);
    // 2. weight transposes -> bf16 (N x K); off/attw weights hi/lo split
    dim3 tb(32, 8);
    transpose_bf16<<<dim3(32, 32), tb, 0, stream>>>(w_value, WvT, 1024, 1024);
    transpose_bf16<<<dim3(32, 32), tb, 0, stream>>>(w_out, WoT, 1024, 1024);
    wsplit_transpose<<<dim3(32, 6), tb, 0, stream>>>(w_off, w_attw, WThi, WTlo);
    // 3. off/attw logits via split-bf16 MFMA (split-K partials)
    offw_mfma<<<dim3(64, 4), 512, 0, stream>>>(query, WThi, WTlo, Part);
    // 4. v = value @ w_value + b_value (bf16 out), rows [1920,4096) per batch
    gemm_bt<false><<<dim3(17, 8, 2), 256, 0, stream>>>(Vbf, WvT, b_value, Vproj, 1920, 4096, 1024, 1024);
    // 5. logits sum + softmax + coefficients + gather -> s (bf16)
    sample_coef<<<8192, 256, 0, stream>>>(Part, b_off, b_attw, Vproj, S);
    // 6. out = s @ w_out + b_out (fp32 out)
    gemm_bt<true><<<dim3(64, 8, 1), 256, 0, stream>>>(S, WoT, b_out, out, 0, 0, 1024, 1024);
}